// Round 13
// baseline (6790.658 us; speedup 1.0000x reference)
//
#include <hip/hip_runtime.h>
#include <hip/hip_bf16.h>
#include <stdint.h>

typedef float  f32x4  __attribute__((ext_vector_type(4)));
typedef short  bf16x8 __attribute__((ext_vector_type(8)));
typedef unsigned int  u32;
typedef unsigned short u16;
typedef unsigned long long u64;

#define BS    64
#define SEQ   1024
#define HID   512

// ---------- helpers ----------
__device__ __forceinline__ u16 f2bf(float f) {
    u32 u = __float_as_uint(f);
    u32 r = (u + 0x7FFFu + ((u >> 16) & 1u)) >> 16;   // RNE
    return (u16)r;
}
__device__ __forceinline__ float bf2f(u16 h) {
    return __uint_as_float(((u32)h) << 16);
}
__device__ __forceinline__ u32 pk2(float a, float b) {
    return (u32)f2bf(a) | ((u32)f2bf(b) << 16);
}
__device__ __forceinline__ float sigm(float x)  { return 1.f / (1.f + __expf(-x)); }
__device__ __forceinline__ float tanh_(float x) { return 1.f - 2.f / (1.f + __expf(2.f * x)); }

// ---------- ws layout ----------
// [0, 2MB)            w4t  bf16 [2048][512]
// [2MB, +8KB)         b4   f32  [2048]
// [.., +256KB)        hb   u64-view [2][4][16][512] u32 words = (h_bf16<<16)|tag
// [.., +128KB)        cbuf f32  [4][16][512]
// [4MB, ...)          xp   bf16 [64*Tc][2048]
#define OFF_W4T   0
#define OFF_B4    (2u*1024*1024)
#define OFF_HB    (OFF_B4 + 8192)
#define OFF_CBUF  (OFF_HB + 262144)
#define OFF_XP    (4u*1024*1024)

// ---------- pack W / bias ----------
__global__ void pack_w(const float* __restrict__ Wi, const float* __restrict__ Wf,
                       const float* __restrict__ Wc, const float* __restrict__ Wo,
                       const float* __restrict__ bi, const float* __restrict__ bf_,
                       const float* __restrict__ bc, const float* __restrict__ bo,
                       u16* __restrict__ w4t, float* __restrict__ b4) {
    int n = blockIdx.x;                 // 0..2047
    int gate = n >> 9, c = n & 511;
    const float* W = (gate == 0) ? Wi : (gate == 1) ? Wf : (gate == 2) ? Wc : Wo;
    const float* B = (gate == 0) ? bi : (gate == 1) ? bf_ : (gate == 2) ? bc : bo;
    int k = threadIdx.x * 2;            // 2 per thread
    u32 v = pk2(W[(size_t)k * 512 + c], W[(size_t)(k + 1) * 512 + c]);
    *(u32*)&w4t[(size_t)n * 512 + k] = v;
    if (threadIdx.x == 0) b4[n] = B[c];
}

// ---------- projection GEMM:  xp[m][n] = bf16( x_row(m) . w4t[n] + b4[n] ) ----------
__global__ __launch_bounds__(256, 2)
void gemm_proj(const float* __restrict__ x, const u16* __restrict__ w4t,
               const float* __restrict__ b4, u16* __restrict__ xp,
               int t0, int Tc) {
    __shared__ __align__(16) u16 lA[128 * 64];
    __shared__ __align__(16) u16 lB[128 * 64];

    int ntb = blockIdx.x & 15;
    int mb  = blockIdx.x >> 4;
    int tps = Tc >> 7;                       // tiles per batch strip
    int bstrip = mb / tps, tb = mb % tps;
    const float* Abase = x + (size_t)(bstrip * SEQ + t0 + tb * 128) * 512;
    size_t xprow0 = (size_t)bstrip * Tc + tb * 128;
    int n0 = ntb * 128;

    int tid = threadIdx.x, lane = tid & 63, w = tid >> 6;
    int wm = w >> 1, wn = w & 1;

    f32x4 acc[4][4];
#pragma unroll
    for (int a = 0; a < 4; a++)
#pragma unroll
        for (int b = 0; b < 4; b++) acc[a][b] = (f32x4){0.f, 0.f, 0.f, 0.f};

    for (int kb = 0; kb < 8; kb++) {
        // stage A (fp32 -> bf16)
        {
            int row = tid >> 1, half = tid & 1;
            const float* src = Abase + (size_t)row * 512 + kb * 64 + half * 32;
            u32 tmp[16];
#pragma unroll
            for (int q = 0; q < 8; q++) {
                float4 f = *(const float4*)(src + q * 4);
                tmp[q * 2]     = pk2(f.x, f.y);
                tmp[q * 2 + 1] = pk2(f.z, f.w);
            }
            u16* dst = &lA[row * 64 + half * 32];
#pragma unroll
            for (int q = 0; q < 4; q++)
                *(uint4*)(dst + q * 8) = *(uint4*)&tmp[q * 4];
        }
        // stage B (already bf16)
        {
            int row = tid >> 1, kc = (tid & 1) * 32;
            const u16* src = w4t + (size_t)(n0 + row) * 512 + kb * 64 + kc;
            uint4 v0 = *(const uint4*)(src);
            uint4 v1 = *(const uint4*)(src + 8);
            uint4 v2 = *(const uint4*)(src + 16);
            uint4 v3 = *(const uint4*)(src + 24);
            u16* dst = &lB[row * 64 + kc];
            *(uint4*)(dst) = v0; *(uint4*)(dst + 8) = v1;
            *(uint4*)(dst + 16) = v2; *(uint4*)(dst + 24) = v3;
        }
        __syncthreads();
#pragma unroll
        for (int kt = 0; kt < 2; kt++) {
            bf16x8 a[4], bb[4];
#pragma unroll
            for (int mt = 0; mt < 4; mt++)
                a[mt] = *(const bf16x8*)&lA[(wm * 64 + mt * 16 + (lane & 15)) * 64 + kt * 32 + (lane >> 4) * 8];
#pragma unroll
            for (int nt = 0; nt < 4; nt++)
                bb[nt] = *(const bf16x8*)&lB[(wn * 64 + nt * 16 + (lane & 15)) * 64 + kt * 32 + (lane >> 4) * 8];
#pragma unroll
            for (int mt = 0; mt < 4; mt++)
#pragma unroll
                for (int nt = 0; nt < 4; nt++)
                    acc[mt][nt] = __builtin_amdgcn_mfma_f32_16x16x32_bf16(a[mt], bb[nt], acc[mt][nt], 0, 0, 0);
        }
        __syncthreads();
    }
    // epilogue: + bias, store bf16
#pragma unroll
    for (int nt = 0; nt < 4; nt++) {
        int n = n0 + wn * 64 + nt * 16 + (lane & 15);
        float bv = b4[n];
#pragma unroll
        for (int mt = 0; mt < 4; mt++)
#pragma unroll
            for (int r = 0; r < 4; r++) {
                size_t m = xprow0 + wm * 64 + mt * 16 + (lane >> 4) * 4 + r;
                xp[m * 2048 + n] = f2bf(acc[mt][nt][r] + bv);
            }
    }
}

// ---------- recurrence: 2 chains/WG, pipelined inline-tagged exchange ----------
// 16 WGs x 256 threads: pr = blockIdx>>3 (pair: chains {2pr, 2pr+1}), q = blockIdx&7
// (64 h-cols). Wave w owns h-cols [q*64+w*16,+16) for all 4 gates of BOTH chains;
// the persistent U slice (ub[16][4]) is shared by both chains (same weights).
// Per iteration: {validate A (read issued one phase earlier) -> stage -> barrier ->
// ISSUE B-read -> MFMA+gates A -> publish A} then same for B with next-A read
// issued before B's MFMA (survives the loop back-edge). Each chain's MALL RT
// (publish-visibility + 16KB read) hides under the other chain's compute.
// Exchange = R3-proven inline-tagged words ((h_bf16<<16)|t+1), relaxed agent
// atomics, double-buffered by t&1; content-validation makes early reads fail-safe
// (re-sweep); monotonic tags -> deadlock-free, chunk- and graph-replay-safe.
__global__ __launch_bounds__(256, 1)
void lstm_rec(const float* __restrict__ U0, const float* __restrict__ U1,
              const float* __restrict__ U2, const float* __restrict__ U3,
              const u16* __restrict__ xp, float* __restrict__ out,
              u64* __restrict__ hb, float* __restrict__ cbuf, int t0, int Tc) {
    const int pr  = blockIdx.x >> 3;
    const int q   = blockIdx.x & 7;
    const int cA  = pr * 2, cB = pr * 2 + 1;
    const int tid = threadIdx.x;
    const int w = tid >> 6, lane = tid & 63;
    const int col16 = lane & 15;
    const int krow  = lane >> 4;                  // 0..3
    const int mycol = q * 64 + w * 16 + col16;    // h-col 0..511

    __shared__ __align__(16) u16 h_lds[2][2][16 * 512];   // [chain][buf], swizzled

    // ---- persistent U fragments: ub[kt][gate] (shared by both chains) ----
    const float* Ug[4] = {U0, U1, U2, U3};
    bf16x8 ub[16][4];
#pragma unroll
    for (int kt = 0; kt < 16; kt++) {
        int kbase = kt * 32 + krow * 8;
#pragma unroll
        for (int g = 0; g < 4; g++) {
            union { u16 sh[8]; bf16x8 v; } uu;
#pragma unroll
            for (int j = 0; j < 8; j++)
                uu.sh[j] = f2bf(Ug[g][(size_t)(kbase + j) * 512 + mycol]);
            ub[kt][g] = uu.v;
        }
    }

    // ---- c state in registers, both chains (rows krow*4+r) ----
    float ccA[4], ccB[4];
    if (t0 == 0) {
#pragma unroll
        for (int r = 0; r < 4; r++) { ccA[r] = 0.f; ccB[r] = 0.f; }
    } else {
#pragma unroll
        for (int r = 0; r < 4; r++) {
            ccA[r] = cbuf[((size_t)cA * 16 + krow * 4 + r) * 512 + mycol];
            ccB[r] = cbuf[((size_t)cB * 16 + krow * 4 + r) * 512 + mycol];
        }
    }

    // helpers (all static indexing)
    auto read16 = [&](u64* vv, const u64* src) {
#pragma unroll
        for (int j = 0; j < 16; j++)
            vv[j] = __hip_atomic_load(src + j * 256, __ATOMIC_RELAXED,
                                      __HIP_MEMORY_SCOPE_AGENT);
    };
    auto tagsbad = [&](const u64* vv, u32 te) -> u32 {
        u32 bad = 0;
#pragma unroll
        for (int j = 0; j < 16; j++) {
            bad |= (((u32)vv[j]) ^ te) & 0xFFFFu;
            bad |= (((u32)(vv[j] >> 32)) ^ te) & 0xFFFFu;
        }
        return bad;
    };
    auto stage16 = [&](const u64* vv, u16* hl) {
#pragma unroll
        for (int j = 0; j < 16; j++) {
            u32 packed = ((u32)vv[j] >> 16) | ((u32)(vv[j] >> 32) & 0xFFFF0000u);
            u32 byte = ((u32)(j * 1024) + (u32)(tid * 4)) ^ ((u32)(j & 7) << 4);
            *(u32*)((char*)hl + byte) = packed;
        }
    };

    u64 v[16];
    // prologue: issue chain-A read for step t0 (tag t0; h_{t0-1})
    {
        const u64* srcA0 = hb + (((size_t)((t0 + 1) & 1)) << 14) + ((size_t)cA << 12) + tid;
        read16(v, srcA0);
    }

    for (int tl = 0; tl < Tc; tl++) {
        const int t = t0 + tl;
        const u32 te = (u32)t & 0xFFFFu;

        // xp prefetch for both chains (HBM latency hides under everything)
        u16 xrA[4][4], xrB[4][4];
#pragma unroll
        for (int g = 0; g < 4; g++)
#pragma unroll
            for (int r = 0; r < 4; r++) {
                xrA[g][r] = xp[(size_t)((cA * 16 + krow * 4 + r) * Tc + tl) * 2048
                               + g * 512 + mycol];
                xrB[g][r] = xp[(size_t)((cB * 16 + krow * 4 + r) * Tc + tl) * 2048
                               + g * 512 + mycol];
            }

        const u64* srcA = hb + (((size_t)((t + 1) & 1)) << 14) + ((size_t)cA << 12) + tid;
        const u64* srcB = hb + (((size_t)((t + 1) & 1)) << 14) + ((size_t)cB << 12) + tid;

        // ======== phase A ========
        while (tagsbad(v, te)) read16(v, srcA);     // first check uses early-issued loads
        stage16(v, &h_lds[0][t & 1][0]);
        __syncthreads();
        read16(v, srcB);                             // ISSUE B-read; hides under MFMA A

        float hvA[4];
        {
            const u16* hl = &h_lds[0][t & 1][0];
            f32x4 acc[4];
#pragma unroll
            for (int g = 0; g < 4; g++) acc[g] = (f32x4){0.f, 0.f, 0.f, 0.f};
#pragma unroll
            for (int kt = 0; kt < 16; kt++) {
                u32 byte = ((u32)(col16 * 1024) + (u32)(kt * 64) + (u32)(krow * 16))
                           ^ ((u32)(col16 & 7) << 4);
                bf16x8 af = *(const bf16x8*)((const char*)hl + byte);
#pragma unroll
                for (int g = 0; g < 4; g++)
                    acc[g] = __builtin_amdgcn_mfma_f32_16x16x32_bf16(af, ub[kt][g], acc[g], 0, 0, 0);
            }
#pragma unroll
            for (int r = 0; r < 4; r++) {
                float zi = acc[0][r] + bf2f(xrA[0][r]);
                float zf = acc[1][r] + bf2f(xrA[1][r]);
                float zg = acc[2][r] + bf2f(xrA[2][r]);
                float zo = acc[3][r] + bf2f(xrA[3][r]);
                float iv = fmaxf(zi, 0.f), fv = fmaxf(zf, 0.f);
                float gv = tanh_(zg), ov = sigm(zo);
                ccA[r] = fv * ccA[r] + iv * gv;
                hvA[r] = ov * tanh_(ccA[r]);
            }
        }
        // publish A (inline-tagged, fire-and-forget)
        {
            const u32 tag = (u32)((t + 1) & 0xFFFF);
            u32* dst = (u32*)(hb + (((size_t)(t & 1) * 4 + cA) << 12));
#pragma unroll
            for (int r = 0; r < 4; r++) {
                int row = krow * 4 + r;
                u32 word = ((u32)f2bf(hvA[r]) << 16) | tag;
                __hip_atomic_store(dst + row * 512 + mycol, word, __ATOMIC_RELAXED,
                                   __HIP_MEMORY_SCOPE_AGENT);
            }
        }
#pragma unroll
        for (int r = 0; r < 4; r++)
            out[(size_t)((cA * 16 + krow * 4 + r) * SEQ + t) * 512 + mycol] = hvA[r];

        // ======== phase B ========
        while (tagsbad(v, te)) read16(v, srcB);
        stage16(v, &h_lds[1][t & 1][0]);
        __syncthreads();
        {   // ISSUE next-A read (step t+1); survives loop back-edge, hides under MFMA B
            const u64* srcA2 = hb + (((size_t)(t & 1)) << 14) + ((size_t)cA << 12) + tid;
            read16(v, srcA2);
        }

        float hvB[4];
        {
            const u16* hl = &h_lds[1][t & 1][0];
            f32x4 acc[4];
#pragma unroll
            for (int g = 0; g < 4; g++) acc[g] = (f32x4){0.f, 0.f, 0.f, 0.f};
#pragma unroll
            for (int kt = 0; kt < 16; kt++) {
                u32 byte = ((u32)(col16 * 1024) + (u32)(kt * 64) + (u32)(krow * 16))
                           ^ ((u32)(col16 & 7) << 4);
                bf16x8 af = *(const bf16x8*)((const char*)hl + byte);
#pragma unroll
                for (int g = 0; g < 4; g++)
                    acc[g] = __builtin_amdgcn_mfma_f32_16x16x32_bf16(af, ub[kt][g], acc[g], 0, 0, 0);
            }
#pragma unroll
            for (int r = 0; r < 4; r++) {
                float zi = acc[0][r] + bf2f(xrB[0][r]);
                float zf = acc[1][r] + bf2f(xrB[1][r]);
                float zg = acc[2][r] + bf2f(xrB[2][r]);
                float zo = acc[3][r] + bf2f(xrB[3][r]);
                float iv = fmaxf(zi, 0.f), fv = fmaxf(zf, 0.f);
                float gv = tanh_(zg), ov = sigm(zo);
                ccB[r] = fv * ccB[r] + iv * gv;
                hvB[r] = ov * tanh_(ccB[r]);
            }
        }
        // publish B
        {
            const u32 tag = (u32)((t + 1) & 0xFFFF);
            u32* dst = (u32*)(hb + (((size_t)(t & 1) * 4 + cB) << 12));
#pragma unroll
            for (int r = 0; r < 4; r++) {
                int row = krow * 4 + r;
                u32 word = ((u32)f2bf(hvB[r]) << 16) | tag;
                __hip_atomic_store(dst + row * 512 + mycol, word, __ATOMIC_RELAXED,
                                   __HIP_MEMORY_SCOPE_AGENT);
            }
        }
#pragma unroll
        for (int r = 0; r < 4; r++)
            out[(size_t)((cB * 16 + krow * 4 + r) * SEQ + t) * 512 + mycol] = hvB[r];
    }

    // save c for next chunk (both chains)
#pragma unroll
    for (int r = 0; r < 4; r++) {
        cbuf[((size_t)cA * 16 + krow * 4 + r) * 512 + mycol] = ccA[r];
        cbuf[((size_t)cB * 16 + krow * 4 + r) * 512 + mycol] = ccB[r];
    }
}

// ---------- launch ----------
extern "C" void kernel_launch(void* const* d_in, const int* in_sizes, int n_in,
                              void* d_out, int out_size, void* d_ws, size_t ws_size,
                              hipStream_t stream) {
    const float* x  = (const float*)d_in[0];
    const float* Wg[4] = {(const float*)d_in[1], (const float*)d_in[4],
                          (const float*)d_in[7], (const float*)d_in[10]};
    const float* Ug[4] = {(const float*)d_in[2], (const float*)d_in[5],
                          (const float*)d_in[8], (const float*)d_in[11]};
    const float* Bg[4] = {(const float*)d_in[3], (const float*)d_in[6],
                          (const float*)d_in[9], (const float*)d_in[12]};
    float* out = (float*)d_out;

    char* ws = (char*)d_ws;
    u16*   w4t   = (u16*)(ws + OFF_W4T);
    float* b4    = (float*)(ws + OFF_B4);
    u64*   hb    = (u64*)(ws + OFF_HB);
    float* cbuf  = (float*)(ws + OFF_CBUF);
    u16*   xp    = (u16*)(ws + OFF_XP);

    // pick chunk length that fits ws
    int Tc = 128;
    for (int c = 1024; c >= 128; c >>= 1)
        if ((size_t)OFF_XP + (size_t)BS * c * 2048 * 2 <= ws_size) { Tc = c; break; }

    // zero inline-tagged hbuf: tag 0 == "h_{-1}=0 ready"
    hipMemsetAsync(ws + OFF_HB, 0, 262144, stream);

    pack_w<<<2048, 256, 0, stream>>>(Wg[0], Wg[1], Wg[2], Wg[3],
                                     Bg[0], Bg[1], Bg[2], Bg[3], w4t, b4);

    for (int t0 = 0; t0 < SEQ; t0 += Tc) {
        dim3 ggrid((unsigned)(BS * (Tc / 128) * 16));
        gemm_proj<<<ggrid, 256, 0, stream>>>(x, w4t, b4, xp, t0, Tc);
        lstm_rec<<<16, 256, 0, stream>>>(Ug[0], Ug[1], Ug[2], Ug[3],
                                         xp, out, hb, cbuf, t0, Tc);
    }
}

// Round 14
// 3992.899 us; speedup vs baseline: 1.7007x; 1.7007x over previous
//
#include <hip/hip_runtime.h>
#include <hip/hip_bf16.h>
#include <stdint.h>

typedef float  f32x4  __attribute__((ext_vector_type(4)));
typedef short  bf16x8 __attribute__((ext_vector_type(8)));
typedef unsigned int  u32;
typedef unsigned short u16;
typedef unsigned long long u64;

#define BS    64
#define SEQ   1024
#define HID   512
#define TCH   64                      // chunk length (xp double-buffer fits ws>=36MB)

// ---------- helpers ----------
__device__ __forceinline__ u16 f2bf(float f) {
    u32 u = __float_as_uint(f);
    u32 r = (u + 0x7FFFu + ((u >> 16) & 1u)) >> 16;   // RNE
    return (u16)r;
}
__device__ __forceinline__ float bf2f(u16 h) {
    return __uint_as_float(((u32)h) << 16);
}
__device__ __forceinline__ u32 pk2(float a, float b) {
    return (u32)f2bf(a) | ((u32)f2bf(b) << 16);
}
__device__ __forceinline__ float sigm(float x)  { return 1.f / (1.f + __expf(-x)); }
__device__ __forceinline__ float tanh_(float x) { return 1.f - 2.f / (1.f + __expf(2.f * x)); }

// ---------- ws layout ----------
// [0, 2MB)            w4t  bf16 [2048][512]
// [2MB, +8KB)         b4   f32  [2048]
// [.., +256KB)        hb   u64-view [2][4][16][512] u32 words = (h_bf16<<16)|tag
// [.., +128KB)        cbuf f32  [4][16][512]
// [4MB, +16MB)        xp0  bf16 [64*TCH][2048]
// [20MB, +16MB)       xp1  bf16 [64*TCH][2048]
#define OFF_W4T   0
#define OFF_B4    (2u*1024*1024)
#define OFF_HB    (OFF_B4 + 8192)
#define OFF_CBUF  (OFF_HB + 262144)
#define OFF_XP0   (4u*1024*1024)
#define OFF_XP1   (20u*1024*1024)

// ---------- pack W / bias ----------
__global__ void pack_w(const float* __restrict__ Wi, const float* __restrict__ Wf,
                       const float* __restrict__ Wc, const float* __restrict__ Wo,
                       const float* __restrict__ bi, const float* __restrict__ bf_,
                       const float* __restrict__ bc, const float* __restrict__ bo,
                       u16* __restrict__ w4t, float* __restrict__ b4) {
    int n = blockIdx.x;                 // 0..2047
    int gate = n >> 9, c = n & 511;
    const float* W = (gate == 0) ? Wi : (gate == 1) ? Wf : (gate == 2) ? Wc : Wo;
    const float* B = (gate == 0) ? bi : (gate == 1) ? bf_ : (gate == 2) ? bc : bo;
    int k = threadIdx.x * 2;            // 2 per thread
    u32 v = pk2(W[(size_t)k * 512 + c], W[(size_t)(k + 1) * 512 + c]);
    *(u32*)&w4t[(size_t)n * 512 + k] = v;
    if (threadIdx.x == 0) b4[n] = B[c];
}

// ---------- projection GEMM role (M-tile 64 x N-tile 128, K=512) ----------
// xp rows are batch-major per chunk: m = bstrip*TCH + (t - t0n)
__device__ __forceinline__ void gemm64_role(int g, const float* __restrict__ x,
                                            const u16* __restrict__ w4t,
                                            const float* __restrict__ b4,
                                            u16* __restrict__ xpn, int t0n,
                                            char* smem) {
    u16* lA = (u16*)smem;            // [64][64]
    u16* lB = (u16*)(smem + 8192);   // [128][64]
    int ntb = g & 15, bstrip = g >> 4;
    const float* Abase = x + (size_t)(bstrip * SEQ + t0n) * 512;
    int n0 = ntb * 128;

    int tid = threadIdx.x, lane = tid & 63, w = tid >> 6;
    int wm = w >> 1, wn = w & 1;

    f32x4 acc[2][4];
#pragma unroll
    for (int a = 0; a < 2; a++)
#pragma unroll
        for (int b = 0; b < 4; b++) acc[a][b] = (f32x4){0.f, 0.f, 0.f, 0.f};

    for (int kb = 0; kb < 8; kb++) {
        // stage A (fp32 -> bf16): 64 rows x 64 cols, 16 elems/thread
        {
            int row = tid >> 2, qd = tid & 3;
            const float* src = Abase + (size_t)row * 512 + kb * 64 + qd * 16;
            u32 tmp[8];
#pragma unroll
            for (int qq = 0; qq < 4; qq++) {
                float4 f = *(const float4*)(src + qq * 4);
                tmp[qq * 2]     = pk2(f.x, f.y);
                tmp[qq * 2 + 1] = pk2(f.z, f.w);
            }
            u16* dst = &lA[row * 64 + qd * 16];
            *(uint4*)(dst)     = *(uint4*)&tmp[0];
            *(uint4*)(dst + 8) = *(uint4*)&tmp[4];
        }
        // stage B (already bf16): 128 rows x 64 cols
        {
            int row = tid >> 1, kc = (tid & 1) * 32;
            const u16* src = w4t + (size_t)(n0 + row) * 512 + kb * 64 + kc;
            uint4 v0 = *(const uint4*)(src);
            uint4 v1 = *(const uint4*)(src + 8);
            uint4 v2 = *(const uint4*)(src + 16);
            uint4 v3 = *(const uint4*)(src + 24);
            u16* dst = &lB[row * 64 + kc];
            *(uint4*)(dst) = v0; *(uint4*)(dst + 8) = v1;
            *(uint4*)(dst + 16) = v2; *(uint4*)(dst + 24) = v3;
        }
        __syncthreads();
#pragma unroll
        for (int kt = 0; kt < 2; kt++) {
            bf16x8 a[2], bb[4];
#pragma unroll
            for (int mt = 0; mt < 2; mt++)
                a[mt] = *(const bf16x8*)&lA[(wm * 32 + mt * 16 + (lane & 15)) * 64 + kt * 32 + (lane >> 4) * 8];
#pragma unroll
            for (int nt = 0; nt < 4; nt++)
                bb[nt] = *(const bf16x8*)&lB[(wn * 64 + nt * 16 + (lane & 15)) * 64 + kt * 32 + (lane >> 4) * 8];
#pragma unroll
            for (int mt = 0; mt < 2; mt++)
#pragma unroll
                for (int nt = 0; nt < 4; nt++)
                    acc[mt][nt] = __builtin_amdgcn_mfma_f32_16x16x32_bf16(a[mt], bb[nt], acc[mt][nt], 0, 0, 0);
        }
        __syncthreads();
    }
    // epilogue: + bias, store bf16
#pragma unroll
    for (int nt = 0; nt < 4; nt++) {
        int n = n0 + wn * 64 + nt * 16 + (lane & 15);
        float bv = b4[n];
#pragma unroll
        for (int mt = 0; mt < 2; mt++)
#pragma unroll
            for (int r = 0; r < 4; r++) {
                size_t m = (size_t)bstrip * TCH + wm * 32 + mt * 16 + (lane >> 4) * 4 + r;
                xpn[m * 2048 + n] = f2bf(acc[mt][nt][r] + bv);
            }
    }
}

// ---------- recurrence role: R3-proven tagged-data exchange + poll backoff ----------
// 32 rec blocks: gid = b>>3 (16 batch rows), q = b&7 (64 h-cols). Wave w owns h-cols
// [q*64+w*16,+16) for all 4 gates; U slice persistent ub[16][4] (256 VGPR).
// Exchange word = (h_bf16<<16)|(t+1), double-buffered by t&1; consumer sweeps
// 16 u64 (128B contig per lane pair-stride, fully coalesced per instr) and
// validates inline tags (combined detect+read, R3). NEW: s_sleep(6) backoff after
// each failed sweep -- R3's counters showed ~10 sweeps/step flooding the MALL/HBM
// path the producer stores also traverse; backoff trades poll BW for visibility.
__device__ __forceinline__ void rec_role(const float* __restrict__ U0,
                                         const float* __restrict__ U1,
                                         const float* __restrict__ U2,
                                         const float* __restrict__ U3,
                                         const u16* __restrict__ xpc,
                                         float* __restrict__ out,
                                         u64* __restrict__ hb,
                                         float* __restrict__ cbuf,
                                         int t0, char* smem) {
    const int gid = blockIdx.x >> 3;
    const int q   = blockIdx.x & 7;
    const int tid = threadIdx.x;
    const int w = tid >> 6, lane = tid & 63;
    const int col16 = lane & 15;
    const int krow  = lane >> 4;                  // 0..3
    const int mycol = q * 64 + w * 16 + col16;    // h-col 0..511

    u16* h_lds = (u16*)smem;                      // [2][16*512], XOR-swizzled

    // ---- persistent U fragments: ub[kt][gate] ----
    const float* Ug[4] = {U0, U1, U2, U3};
    bf16x8 ub[16][4];
#pragma unroll
    for (int kt = 0; kt < 16; kt++) {
        int kbase = kt * 32 + krow * 8;
#pragma unroll
        for (int g = 0; g < 4; g++) {
            union { u16 sh[8]; bf16x8 v; } uu;
#pragma unroll
            for (int j = 0; j < 8; j++)
                uu.sh[j] = f2bf(Ug[g][(size_t)(kbase + j) * 512 + mycol]);
            ub[kt][g] = uu.v;
        }
    }

    // ---- c state in registers (rows krow*4+r) ----
    float c[4];
    if (t0 == 0) {
        c[0] = c[1] = c[2] = c[3] = 0.f;
    } else {
#pragma unroll
        for (int r = 0; r < 4; r++)
            c[r] = cbuf[((size_t)gid * 16 + krow * 4 + r) * 512 + mycol];
    }

    for (int tl = 0; tl < TCH; tl++) {
        const int t = t0 + tl;

        // ---- xp prefetch (independent of exchange; HBM latency overlaps poll) ----
        u16 xr[4][4];
#pragma unroll
        for (int g = 0; g < 4; g++)
#pragma unroll
            for (int r = 0; r < 4; r++)
                xr[g][r] = xpc[(size_t)((gid * 16 + krow * 4 + r) * TCH + tl) * 2048
                               + g * 512 + mycol];

        // ---- tagged spin-load of h_{t-1} (combined detect+read, R3-proven) ----
        u64 v[16];
        {
            const u64* src = hb + (((size_t)((t + 1) & 1)) << 14) + ((size_t)gid << 12) + tid;
            const u32 te = (u32)t & 0xFFFFu;
            for (;;) {
#pragma unroll
                for (int j = 0; j < 16; j++)
                    v[j] = __hip_atomic_load(src + j * 256, __ATOMIC_RELAXED,
                                             __HIP_MEMORY_SCOPE_AGENT);
                u32 bad = 0;
#pragma unroll
                for (int j = 0; j < 16; j++) {
                    bad |= (((u32)v[j]) ^ te) & 0xFFFFu;
                    bad |= (((u32)(v[j] >> 32)) ^ te) & 0xFFFFu;
                }
                if (!bad) break;
                __builtin_amdgcn_s_sleep(6);   // backoff: cut poll flood ~3x
            }
        }

        // ---- stage to LDS (buffer t&1), swizzled ----
        u16* hl = h_lds + (t & 1) * 8192;
#pragma unroll
        for (int j = 0; j < 16; j++) {
            u32 packed = ((u32)v[j] >> 16) | ((u32)(v[j] >> 32) & 0xFFFF0000u);
            u32 byte = ((u32)(j * 1024) + (u32)(tid * 4)) ^ ((u32)(j & 7) << 4);
            *(u32*)((char*)hl + byte) = packed;
        }
        __syncthreads();

        // ---- z = h @ U : 64 MFMAs/wave, gates in-register ----
        f32x4 acc[4];
#pragma unroll
        for (int g = 0; g < 4; g++) acc[g] = (f32x4){0.f, 0.f, 0.f, 0.f};
#pragma unroll
        for (int kt = 0; kt < 16; kt++) {
            u32 byte = ((u32)(col16 * 1024) + (u32)(kt * 64) + (u32)(krow * 16))
                       ^ ((u32)(col16 & 7) << 4);
            bf16x8 af = *(const bf16x8*)((const char*)hl + byte);
#pragma unroll
            for (int g = 0; g < 4; g++)
                acc[g] = __builtin_amdgcn_mfma_f32_16x16x32_bf16(af, ub[kt][g], acc[g], 0, 0, 0);
        }

        // ---- gates ----
        float hv[4];
#pragma unroll
        for (int r = 0; r < 4; r++) {
            float zi = acc[0][r] + bf2f(xr[0][r]);
            float zf = acc[1][r] + bf2f(xr[1][r]);
            float zg = acc[2][r] + bf2f(xr[2][r]);
            float zo = acc[3][r] + bf2f(xr[3][r]);
            float iv = fmaxf(zi, 0.f), fv = fmaxf(zf, 0.f);
            float gv = tanh_(zg), ov = sigm(zo);
            c[r] = fv * c[r] + iv * gv;
            hv[r] = ov * tanh_(c[r]);
        }

        // ---- publish tagged h_t (fire-and-forget) ----
        {
            const u32 tag = (u32)((t + 1) & 0xFFFF);
            u32* dst = (u32*)(hb + (((size_t)(t & 1) * 4 + gid) << 12));
#pragma unroll
            for (int r = 0; r < 4; r++) {
                int row = krow * 4 + r;
                u32 word = ((u32)f2bf(hv[r]) << 16) | tag;
                __hip_atomic_store(dst + row * 512 + mycol, word, __ATOMIC_RELAXED,
                                   __HIP_MEMORY_SCOPE_AGENT);
            }
        }

        // ---- output stores (off critical path) ----
#pragma unroll
        for (int r = 0; r < 4; r++)
            out[(size_t)((gid * 16 + krow * 4 + r) * SEQ + t) * 512 + mycol] = hv[r];
    }

    // save c for next chunk
#pragma unroll
    for (int r = 0; r < 4; r++)
        cbuf[((size_t)gid * 16 + krow * 4 + r) * 512 + mycol] = c[r];
}

// ---------- standalone GEMM kernel (chunk 0 boot) ----------
__global__ __launch_bounds__(256, 2)
void gemm_boot(const float* __restrict__ x, const u16* __restrict__ w4t,
               const float* __restrict__ b4, u16* __restrict__ xpn, int t0n) {
    __shared__ __align__(16) char smem[24576];
    gemm64_role(blockIdx.x, x, w4t, b4, xpn, t0n, smem);
}

// ---------- fused kernel: rec(chunk ci) + gemm(chunk ci+1) on idle CUs ----------
__global__ __launch_bounds__(256, 1)
void fused_step(const float* __restrict__ U0, const float* __restrict__ U1,
                const float* __restrict__ U2, const float* __restrict__ U3,
                const float* __restrict__ x, const u16* __restrict__ w4t,
                const float* __restrict__ b4,
                const u16* __restrict__ xpc, u16* __restrict__ xpn,
                float* __restrict__ out, u64* __restrict__ hb,
                float* __restrict__ cbuf, int t0) {
    __shared__ __align__(16) char smem[32768];
    if (blockIdx.x < 32) {
        rec_role(U0, U1, U2, U3, xpc, out, hb, cbuf, t0, smem);
    } else {
        gemm64_role((int)blockIdx.x - 32, x, w4t, b4, xpn, t0 + TCH, smem);
    }
}

// ---------- launch ----------
extern "C" void kernel_launch(void* const* d_in, const int* in_sizes, int n_in,
                              void* d_out, int out_size, void* d_ws, size_t ws_size,
                              hipStream_t stream) {
    const float* x  = (const float*)d_in[0];
    const float* Wg[4] = {(const float*)d_in[1], (const float*)d_in[4],
                          (const float*)d_in[7], (const float*)d_in[10]};
    const float* Ug[4] = {(const float*)d_in[2], (const float*)d_in[5],
                          (const float*)d_in[8], (const float*)d_in[11]};
    const float* Bg[4] = {(const float*)d_in[3], (const float*)d_in[6],
                          (const float*)d_in[9], (const float*)d_in[12]};
    float* out = (float*)d_out;

    char* ws = (char*)d_ws;
    u16*   w4t   = (u16*)(ws + OFF_W4T);
    float* b4    = (float*)(ws + OFF_B4);
    u64*   hb    = (u64*)(ws + OFF_HB);
    float* cbuf  = (float*)(ws + OFF_CBUF);
    u16*   xp0   = (u16*)(ws + OFF_XP0);
    u16*   xp1   = (u16*)(ws + OFF_XP1);

    // zero tagged hbuf: tag 0 == "h_{-1} ready, value 0"
    hipMemsetAsync(ws + OFF_HB, 0, 262144, stream);

    pack_w<<<2048, 256, 0, stream>>>(Wg[0], Wg[1], Wg[2], Wg[3],
                                     Bg[0], Bg[1], Bg[2], Bg[3], w4t, b4);

    const int nch = SEQ / TCH;                        // 16 chunks
    // boot: projection for chunk 0
    gemm_boot<<<64 * 16, 256, 0, stream>>>(x, w4t, b4, xp0, 0);

    for (int ci = 0; ci < nch; ci++) {
        u16* xpc = (ci & 1) ? xp1 : xp0;
        u16* xpn = (ci & 1) ? xp0 : xp1;
        int  nb  = 32 + ((ci + 1 < nch) ? 64 * 16 : 0);
        fused_step<<<nb, 256, 0, stream>>>(Ug[0], Ug[1], Ug[2], Ug[3],
                                           x, w4t, b4, xpc, xpn,
                                           out, hb, cbuf, ci * TCH);
    }
}